// Round 1
// baseline (307.215 us; speedup 1.0000x reference)
//
#include <hip/hip_runtime.h>
#include <hip/hip_bf16.h>

typedef __bf16 bf16;
typedef __bf16 bf16x4 __attribute__((ext_vector_type(4)));
typedef __bf16 bf16x8 __attribute__((ext_vector_type(8)));
typedef float  f32x4  __attribute__((ext_vector_type(4)));
typedef unsigned int u32;

#define B_   2
#define SQ_  2048
#define SK_  2048
#define H_   2048
#define NH_  16
#define HD_  128
#define BH_  (B_*NH_)

// async 16B global->LDS; LDS dest must be wave-uniform base (+lane*16 by HW)
__device__ inline void gl_lds16(const bf16* g, bf16* l) {
  __builtin_amdgcn_global_load_lds(
      (const __attribute__((address_space(1))) u32*)(const void*)g,
      (__attribute__((address_space(3))) u32*)(void*)l,
      16, 0, 0);
}

__device__ inline float exp2_fast(float x) {
  float r; asm("v_exp_f32 %0, %1" : "=v"(r) : "v"(x)); return r;
}

// ---------------- fp32 -> bf16 convert (vectorized) ----------------
__global__ __launch_bounds__(256) void cvt_f32_bf16(const float* __restrict__ in,
                                                    bf16* __restrict__ out, int n4) {
  int i = blockIdx.x * blockDim.x + threadIdx.x;
  int stride = gridDim.x * blockDim.x;
  for (; i < n4; i += stride) {
    float4 v = ((const float4*)in)[i];
    bf16x4 w; w[0] = (bf16)v.x; w[1] = (bf16)v.y; w[2] = (bf16)v.z; w[3] = (bf16)v.w;
    ((bf16x4*)out)[i] = w;
  }
}

// ------------- per-slice transpose + convert: in[bh][R][C] f32 -> out[bh][C][R] bf16
__global__ __launch_bounds__(256) void transpose_cvt(const float* __restrict__ in,
                                                     bf16* __restrict__ out, int R, int C) {
  __shared__ float tile[64][65];
  const int bh = blockIdx.z;
  const int r0 = blockIdx.y * 64, c0 = blockIdx.x * 64;
  const float* src = in + (size_t)bh * R * C;
  bf16* dst = out + (size_t)bh * R * C;
  const int t = threadIdx.x;
  const int tx = t & 15, ty = t >> 4;
#pragma unroll
  for (int p = 0; p < 4; ++p) {
    int rr = ty + p * 16;
    float4 v = *(const float4*)&src[(size_t)(r0 + rr) * C + c0 + tx * 4];
    tile[rr][tx * 4 + 0] = v.x; tile[rr][tx * 4 + 1] = v.y;
    tile[rr][tx * 4 + 2] = v.z; tile[rr][tx * 4 + 3] = v.w;
  }
  __syncthreads();
#pragma unroll
  for (int p = 0; p < 4; ++p) {
    int cc = ty + p * 16;
    bf16x4 w;
#pragma unroll
    for (int i = 0; i < 4; ++i) w[i] = (bf16)tile[tx * 4 + i][cc];
    *(bf16x4*)&dst[(size_t)(c0 + cc) * R + r0 + tx * 4] = w;
  }
}

// ---------------- 128x128-tile bf16 GEMM, C = A @ Bw^T + bias ----------------
// A[M][K], Bw[N][K] row-major bf16; C row-major OutT. 256 threads (2x2 waves).
template <typename OutT>
__global__ __launch_bounds__(256) void gemm_bt(const bf16* __restrict__ A,
                                               const bf16* __restrict__ Bw,
                                               const float* __restrict__ bias,
                                               OutT* __restrict__ C,
                                               int M, int N, int K) {
  __shared__ bf16 Abuf[128 * 32];
  __shared__ bf16 Bbuf[128 * 32];
  const int nbn = N >> 7;
  int wg = blockIdx.x, nwg = gridDim.x;
  int swz = (nwg & 7) ? wg : ((wg & 7) * (nwg >> 3) + (wg >> 3));  // XCD swizzle
  int bm = swz / nbn, bn = swz % nbn;
  const int t = threadIdx.x, lane = t & 63, wid = t >> 6;
  const int r = lane & 15, g = lane >> 4;
  const int wr = wid >> 1, wc = wid & 1;
  const size_t m0 = (size_t)bm * 128, n0 = (size_t)bn * 128;

  f32x4 acc[4][4];
#pragma unroll
  for (int m = 0; m < 4; ++m)
#pragma unroll
    for (int n = 0; n < 4; ++n) acc[m][n] = (f32x4){0.f, 0.f, 0.f, 0.f};

  for (int k0 = 0; k0 < K; k0 += 32) {
    __syncthreads();
#pragma unroll
    for (int p = 0; p < 2; ++p) {
      int c = p * 256 + t;
      int row = c >> 2, off = c & 3;  // 128 rows x 4 16B-chunks
      gl_lds16(A + (m0 + row) * K + k0 + off * 8, &Abuf[(p * 256 + wid * 64) * 8]);
      gl_lds16(Bw + (n0 + row) * K + k0 + off * 8, &Bbuf[(p * 256 + wid * 64) * 8]);
    }
    __syncthreads();
    bf16x8 af[4], bfr[4];
#pragma unroll
    for (int m = 0; m < 4; ++m)
      af[m] = *(const bf16x8*)&Abuf[(wr * 64 + m * 16 + r) * 32 + g * 8];
#pragma unroll
    for (int n = 0; n < 4; ++n)
      bfr[n] = *(const bf16x8*)&Bbuf[(wc * 64 + n * 16 + r) * 32 + g * 8];
#pragma unroll
    for (int m = 0; m < 4; ++m)
#pragma unroll
      for (int n = 0; n < 4; ++n)
        acc[m][n] = __builtin_amdgcn_mfma_f32_16x16x32_bf16(af[m], bfr[n], acc[m][n], 0, 0, 0);
  }

  float bv[4];
#pragma unroll
  for (int n = 0; n < 4; ++n) bv[n] = bias[n0 + wc * 64 + n * 16 + r];
#pragma unroll
  for (int m = 0; m < 4; ++m)
#pragma unroll
    for (int n = 0; n < 4; ++n)
#pragma unroll
      for (int rr = 0; rr < 4; ++rr) {
        size_t row = m0 + wr * 64 + m * 16 + g * 4 + rr;
        size_t col = n0 + wc * 64 + n * 16 + r;
        C[row * N + col] = (OutT)(acc[m][n][rr] + bv[n]);
      }
}

// ---------------- causal flash attention ----------------
// Q[b][q][h*128+d] bf16, Kt[bh][s][d] bf16, Vt[bh][d][s] bf16 -> O[b][q][h*128+d] bf16
// grid (SQ/64, BH), 256 threads; wave wid owns q-rows [wid*16, wid*16+16)
__global__ __launch_bounds__(256) void flash_attn(const bf16* __restrict__ Q,
                                                  const bf16* __restrict__ Kt,
                                                  const bf16* __restrict__ Vt,
                                                  bf16* __restrict__ O) {
  __shared__ bf16 Klds[64 * 128];   // [s][d], chunk-XOR-swizzled
  __shared__ bf16 Vlds[128 * 64];   // [d][s], chunk-XOR-swizzled
  __shared__ bf16 Plds[4][16 * 72]; // per-wave P re-layout, padded rows

  const int qt = (int)gridDim.x - 1 - (int)blockIdx.x;  // heavy tiles first
  const int bh = blockIdx.y;
  const int b = bh >> 4, h = bh & 15;
  const int t = threadIdx.x, lane = t & 63, wid = t >> 6;
  const int r = lane & 15, g = lane >> 4;
  const int q0 = qt * 64;

  // Q fragments hoisted to registers (K=128 -> 4 chunks of 32)
  const size_t qrow = ((size_t)(b * SQ_ + q0 + wid * 16 + r)) * H_ + (size_t)h * HD_;
  bf16x8 qf[4];
#pragma unroll
  for (int kk = 0; kk < 4; ++kk) qf[kk] = *(const bf16x8*)&Q[qrow + kk * 32 + g * 8];

  f32x4 acc[8];
#pragma unroll
  for (int i = 0; i < 8; ++i) acc[i] = (f32x4){0.f, 0.f, 0.f, 0.f};
  float mrun[4], lrun[4];
#pragma unroll
  for (int i = 0; i < 4; ++i) { mrun[i] = -3.0e38f; lrun[i] = 0.f; }

  const float SC2 = 0.08838834764831845f * 1.4426950408889634f;  // 1/sqrt(128) * log2(e)
  const bf16* Kbase = Kt + (size_t)bh * SK_ * HD_;
  const bf16* Vbase = Vt + (size_t)bh * HD_ * SK_;

  for (int st = 0; st <= qt; ++st) {
    const int s0 = st * 64;
    __syncthreads();
    // stage K tile (64 rows x 256B = 1024 chunks) + V tile (128 rows x 128B = 1024 chunks)
    // linear LDS dest + inverse-swizzled global source; reads apply the same XOR.
#pragma unroll
    for (int p = 0; p < 4; ++p) {
      int c = p * 256 + t;
      { int row = c >> 4, off = c & 15, src = off ^ (row & 7);
        gl_lds16(Kbase + (size_t)(s0 + row) * HD_ + src * 8, &Klds[(p * 256 + wid * 64) * 8]); }
      { int row = c >> 3, off = c & 7, src = off ^ (row & 7);
        gl_lds16(Vbase + (size_t)row * SK_ + s0 + src * 8, &Vlds[(p * 256 + wid * 64) * 8]); }
    }
    __syncthreads();

    // S = Q K^T  (A=Q, B=K^T from Klds[s][d])
    f32x4 s[4];
#pragma unroll
    for (int sb = 0; sb < 4; ++sb) s[sb] = (f32x4){0.f, 0.f, 0.f, 0.f};
#pragma unroll
    for (int sb = 0; sb < 4; ++sb) {
      const int srow = sb * 16 + r;
#pragma unroll
      for (int kk = 0; kk < 4; ++kk) {
        bf16x8 kf = *(const bf16x8*)&Klds[srow * 128 + (((kk * 4 + g) ^ (srow & 7)) * 8)];
        s[sb] = __builtin_amdgcn_mfma_f32_16x16x32_bf16(qf[kk], kf, s[sb], 0, 0, 0);
      }
    }

    // scale to log2-domain + causal mask on diagonal tile
    float sv[4][4];
#pragma unroll
    for (int sb = 0; sb < 4; ++sb)
#pragma unroll
      for (int rr = 0; rr < 4; ++rr) {
        float x = s[sb][rr] * SC2;
        if (st == qt) {
          int s_loc = sb * 16 + r, q_loc = wid * 16 + g * 4 + rr;
          if (s_loc > q_loc) x = -3.0e38f;
        }
        sv[sb][rr] = x;
      }

    // online softmax (rows live in 16-lane groups)
    float mnew[4], corr[4];
#pragma unroll
    for (int rr = 0; rr < 4; ++rr) {
      float mx = fmaxf(fmaxf(sv[0][rr], sv[1][rr]), fmaxf(sv[2][rr], sv[3][rr]));
#pragma unroll
      for (int d = 1; d < 16; d <<= 1) mx = fmaxf(mx, __shfl_xor(mx, d));
      mnew[rr] = fmaxf(mrun[rr], mx);
      corr[rr] = exp2_fast(mrun[rr] - mnew[rr]);
      mrun[rr] = mnew[rr];
    }
    float pv[4][4];
#pragma unroll
    for (int sb = 0; sb < 4; ++sb)
#pragma unroll
      for (int rr = 0; rr < 4; ++rr) pv[sb][rr] = exp2_fast(sv[sb][rr] - mnew[rr]);
#pragma unroll
    for (int rr = 0; rr < 4; ++rr) {
      float sum = (pv[0][rr] + pv[1][rr]) + (pv[2][rr] + pv[3][rr]);
#pragma unroll
      for (int d = 1; d < 16; d <<= 1) sum += __shfl_xor(sum, d);
      lrun[rr] = lrun[rr] * corr[rr] + sum;
    }
#pragma unroll
    for (int nb = 0; nb < 8; ++nb)
#pragma unroll
      for (int rr = 0; rr < 4; ++rr) acc[nb][rr] *= corr[rr];

    // P: C-frag layout -> A-frag layout via per-wave LDS round-trip
#pragma unroll
    for (int sb = 0; sb < 4; ++sb)
#pragma unroll
      for (int rr = 0; rr < 4; ++rr)
        Plds[wid][(g * 4 + rr) * 72 + sb * 16 + r] = (bf16)pv[sb][rr];
    bf16x8 pa[2];
#pragma unroll
    for (int k2 = 0; k2 < 2; ++k2)
      pa[k2] = *(const bf16x8*)&Plds[wid][r * 72 + k2 * 32 + g * 8];

    // O += P V  (B = V from Vlds[d][s])
#pragma unroll
    for (int nb = 0; nb < 8; ++nb) {
      const int drow = nb * 16 + r;
#pragma unroll
      for (int k2 = 0; k2 < 2; ++k2) {
        bf16x8 vf = *(const bf16x8*)&Vlds[drow * 64 + (((k2 * 4 + g) ^ (drow & 7)) * 8)];
        acc[nb] = __builtin_amdgcn_mfma_f32_16x16x32_bf16(pa[k2], vf, acc[nb], 0, 0, 0);
      }
    }
  }

  float inv[4];
#pragma unroll
  for (int rr = 0; rr < 4; ++rr) inv[rr] = 1.0f / lrun[rr];
#pragma unroll
  for (int nb = 0; nb < 8; ++nb)
#pragma unroll
    for (int rr = 0; rr < 4; ++rr) {
      size_t row = (size_t)(b * SQ_ + q0 + wid * 16 + g * 4 + rr);
      O[row * H_ + (size_t)h * HD_ + nb * 16 + r] = (bf16)(acc[nb][rr] * inv[rr]);
    }
}

extern "C" void kernel_launch(void* const* d_in, const int* in_sizes, int n_in,
                              void* d_out, int out_size, void* d_ws, size_t ws_size,
                              hipStream_t stream) {
  const float* hidden = (const float*)d_in[0];
  const float* key    = (const float*)d_in[1];
  const float* value  = (const float*)d_in[2];
  // d_in[3] = attention_mask: pure causal additive mask, applied analytically
  const float* w_q    = (const float*)d_in[4];
  const float* b_q    = (const float*)d_in[5];
  const float* w_proj = (const float*)d_in[6];
  const float* b_proj = (const float*)d_in[7];
  float* out = (float*)d_out;

  const size_t N_HID = (size_t)B_ * SQ_ * H_;      // 8388608
  const size_t N_W   = (size_t)H_ * H_;            // 4194304
  const size_t N_KV  = (size_t)BH_ * SK_ * HD_;    // 8388608

  bf16* hid_bf  = (bf16*)d_ws;            // [B*SQ][H]
  bf16* wq_bf   = hid_bf + N_HID;         // [H][H]
  bf16* wp_bf   = wq_bf + N_W;            // [H][H]
  bf16* k_bf    = wp_bf + N_W;            // [BH][SK][HD]
  bf16* vt_bf   = k_bf + N_KV;            // [BH][HD][SK]
  bf16* q_bf    = vt_bf + N_KV;           // [B*SQ][H]
  bf16* attn_bf = hid_bf;                 // alias: hidden consumed after GEMM1

  cvt_f32_bf16<<<2048, 256, 0, stream>>>(hidden, hid_bf, (int)(N_HID / 4));
  cvt_f32_bf16<<<1024, 256, 0, stream>>>(w_q, wq_bf, (int)(N_W / 4));
  cvt_f32_bf16<<<1024, 256, 0, stream>>>(w_proj, wp_bf, (int)(N_W / 4));
  // key [bh][HD][SK] -> k_bf [bh][SK][HD]
  transpose_cvt<<<dim3(SK_ / 64, HD_ / 64, BH_), 256, 0, stream>>>(key, k_bf, HD_, SK_);
  // value [bh][SK][HD] -> vt_bf [bh][HD][SK]
  transpose_cvt<<<dim3(HD_ / 64, SK_ / 64, BH_), 256, 0, stream>>>(value, vt_bf, SK_, HD_);

  // Q = hidden @ w_q^T + b_q  (bf16 out)
  gemm_bt<bf16><<<(B_ * SQ_ / 128) * (H_ / 128), 256, 0, stream>>>(
      hid_bf, wq_bf, b_q, q_bf, B_ * SQ_, H_, H_);

  flash_attn<<<dim3(SQ_ / 64, BH_), 256, 0, stream>>>(q_bf, k_bf, vt_bf, attn_bf);

  // out = attn @ w_proj^T + b_proj  (fp32 out)
  gemm_bt<float><<<(B_ * SQ_ / 128) * (H_ / 128), 256, 0, stream>>>(
      attn_bf, wp_bf, b_proj, out, B_ * SQ_, H_, H_);
}

// Round 2
// 231.345 us; speedup vs baseline: 1.3279x; 1.3279x over previous
//
#include <hip/hip_runtime.h>
#include <hip/hip_bf16.h>

typedef __bf16 bf16;
typedef __bf16 bf16x4 __attribute__((ext_vector_type(4)));
typedef __bf16 bf16x8 __attribute__((ext_vector_type(8)));
typedef float  f32x4  __attribute__((ext_vector_type(4)));
typedef unsigned int u32;

#define B_   2
#define SQ_  2048
#define SK_  2048
#define H_   2048
#define NH_  16
#define HD_  128
#define BH_  (B_*NH_)

// async 16B global->LDS; LDS dest must be wave-uniform base (+lane*16 by HW)
__device__ inline void gl_lds16(const bf16* g, bf16* l) {
  __builtin_amdgcn_global_load_lds(
      (const __attribute__((address_space(1))) u32*)(const void*)g,
      (__attribute__((address_space(3))) u32*)(void*)l,
      16, 0, 0);
}

__device__ inline float exp2_fast(float x) {
  float r; asm("v_exp_f32 %0, %1" : "=v"(r) : "v"(x)); return r;
}

// ---------------- fp32 -> bf16 convert (vectorized) ----------------
__global__ __launch_bounds__(256) void cvt_f32_bf16(const float* __restrict__ in,
                                                    bf16* __restrict__ out, int n4) {
  int i = blockIdx.x * blockDim.x + threadIdx.x;
  int stride = gridDim.x * blockDim.x;
  for (; i < n4; i += stride) {
    float4 v = ((const float4*)in)[i];
    bf16x4 w; w[0] = (bf16)v.x; w[1] = (bf16)v.y; w[2] = (bf16)v.z; w[3] = (bf16)v.w;
    ((bf16x4*)out)[i] = w;
  }
}

// ------------- per-slice transpose + convert: in[bh][R][C] f32 -> out[bh][C][R] bf16
__global__ __launch_bounds__(256) void transpose_cvt(const float* __restrict__ in,
                                                     bf16* __restrict__ out, int R, int C) {
  __shared__ float tile[64][65];
  const int bh = blockIdx.z;
  const int r0 = blockIdx.y * 64, c0 = blockIdx.x * 64;
  const float* src = in + (size_t)bh * R * C;
  bf16* dst = out + (size_t)bh * R * C;
  const int t = threadIdx.x;
  const int tx = t & 15, ty = t >> 4;
#pragma unroll
  for (int p = 0; p < 4; ++p) {
    int rr = ty + p * 16;
    float4 v = *(const float4*)&src[(size_t)(r0 + rr) * C + c0 + tx * 4];
    tile[rr][tx * 4 + 0] = v.x; tile[rr][tx * 4 + 1] = v.y;
    tile[rr][tx * 4 + 2] = v.z; tile[rr][tx * 4 + 3] = v.w;
  }
  __syncthreads();
#pragma unroll
  for (int p = 0; p < 4; ++p) {
    int cc = ty + p * 16;
    bf16x4 w;
#pragma unroll
    for (int i = 0; i < 4; ++i) w[i] = (bf16)tile[tx * 4 + i][cc];
    *(bf16x4*)&dst[(size_t)(c0 + cc) * R + r0 + tx * 4] = w;
  }
}

// ---------------- 128x128-tile bf16 GEMM, C = A @ Bw^T + bias ----------------
template <typename OutT>
__global__ __launch_bounds__(256) void gemm_bt(const bf16* __restrict__ A,
                                               const bf16* __restrict__ Bw,
                                               const float* __restrict__ bias,
                                               OutT* __restrict__ C,
                                               int M, int N, int K) {
  __shared__ bf16 Abuf[128 * 32];
  __shared__ bf16 Bbuf[128 * 32];
  const int nbn = N >> 7;
  int wg = blockIdx.x, nwg = gridDim.x;
  int swz = (nwg & 7) ? wg : ((wg & 7) * (nwg >> 3) + (wg >> 3));  // XCD swizzle
  int bm = swz / nbn, bn = swz % nbn;
  const int t = threadIdx.x, lane = t & 63, wid = t >> 6;
  const int r = lane & 15, g = lane >> 4;
  const int wr = wid >> 1, wc = wid & 1;
  const size_t m0 = (size_t)bm * 128, n0 = (size_t)bn * 128;

  f32x4 acc[4][4];
#pragma unroll
  for (int m = 0; m < 4; ++m)
#pragma unroll
    for (int n = 0; n < 4; ++n) acc[m][n] = (f32x4){0.f, 0.f, 0.f, 0.f};

  for (int k0 = 0; k0 < K; k0 += 32) {
    __syncthreads();
#pragma unroll
    for (int p = 0; p < 2; ++p) {
      int c = p * 256 + t;
      int row = c >> 2, off = c & 3;  // 128 rows x 4 16B-chunks
      gl_lds16(A + (m0 + row) * K + k0 + off * 8, &Abuf[(p * 256 + wid * 64) * 8]);
      gl_lds16(Bw + (n0 + row) * K + k0 + off * 8, &Bbuf[(p * 256 + wid * 64) * 8]);
    }
    __syncthreads();
    bf16x8 af[4], bfr[4];
#pragma unroll
    for (int m = 0; m < 4; ++m)
      af[m] = *(const bf16x8*)&Abuf[(wr * 64 + m * 16 + r) * 32 + g * 8];
#pragma unroll
    for (int n = 0; n < 4; ++n)
      bfr[n] = *(const bf16x8*)&Bbuf[(wc * 64 + n * 16 + r) * 32 + g * 8];
#pragma unroll
    for (int m = 0; m < 4; ++m)
#pragma unroll
      for (int n = 0; n < 4; ++n)
        acc[m][n] = __builtin_amdgcn_mfma_f32_16x16x32_bf16(af[m], bfr[n], acc[m][n], 0, 0, 0);
  }

  float bv[4];
#pragma unroll
  for (int n = 0; n < 4; ++n) bv[n] = bias[n0 + wc * 64 + n * 16 + r];
#pragma unroll
  for (int m = 0; m < 4; ++m)
#pragma unroll
    for (int n = 0; n < 4; ++n)
#pragma unroll
      for (int rr = 0; rr < 4; ++rr) {
        size_t row = m0 + wr * 64 + m * 16 + g * 4 + rr;
        size_t col = n0 + wc * 64 + n * 16 + r;
        C[row * N + col] = (OutT)(acc[m][n][rr] + bv[n]);
      }
}

// ---------------- causal flash attention (paired tiles, dbuf, XCD-local) ----
// Q[b][q][h*128+d] bf16, Kt[bh][s][d] bf16, Vt[bh][d][s] bf16 -> O[b][q][h*128+d] bf16
// grid 512 blocks, 256 threads. Block id: xcd=id&7, j=id>>3; bh=xcd+8*(j>>4),
// pr=j&15. Processes q-tiles (31-pr) then (pr): uniform 33 K/V-tile iters.
__global__ __launch_bounds__(256) void flash_attn(const bf16* __restrict__ Q,
                                                  const bf16* __restrict__ Kt,
                                                  const bf16* __restrict__ Vt,
                                                  bf16* __restrict__ O) {
  __shared__ bf16 Klds[2][64 * 128];   // [s][d], chunk-XOR-swizzled
  __shared__ bf16 Vlds[2][128 * 64];   // [d][s], chunk-XOR-swizzled
  __shared__ bf16 Plds[4][16 * 72];    // per-wave P re-layout, padded rows

  const int id = blockIdx.x;
  const int bh = (id & 7) + 8 * ((id >> 3) >> 4);
  const int pr = (id >> 3) & 15;
  const int b = bh >> 4, h = bh & 15;
  const int t = threadIdx.x, lane = t & 63, wid = t >> 6;
  const int r = lane & 15, g = lane >> 4;

  const float SC2 = 0.08838834764831845f * 1.4426950408889634f;  // 1/sqrt(128)*log2e
  const bf16* Kbase = Kt + (size_t)bh * SK_ * HD_;
  const bf16* Vbase = Vt + (size_t)bh * HD_ * SK_;

  // precomputed per-thread staging source offsets (linear LDS dest + inverse-
  // swizzled global source; reads apply the same XOR)
  size_t kSrc[4], vSrc[4];
#pragma unroll
  for (int p = 0; p < 4; ++p) {
    int c = p * 256 + t;
    { int row = c >> 4, off = c & 15, src = off ^ (row & 7);
      kSrc[p] = (size_t)row * HD_ + src * 8; }
    { int row = c >> 3, off = c & 7, src = off ^ (row & 7);
      vSrc[p] = (size_t)row * SK_ + src * 8; }
  }

  int cur = 0;
#pragma unroll 1
  for (int pass = 0; pass < 2; ++pass) {
    const int qt = pass ? pr : 31 - pr;
    const int q0 = qt * 64;

    // Q fragments for this tile (K=128 -> 4 chunks of 32)
    const size_t qrow = ((size_t)(b * SQ_ + q0 + wid * 16 + r)) * H_ + (size_t)h * HD_;
    bf16x8 qf[4];
#pragma unroll
    for (int kk = 0; kk < 4; ++kk) qf[kk] = *(const bf16x8*)&Q[qrow + kk * 32 + g * 8];

    f32x4 acc[8];
#pragma unroll
    for (int i = 0; i < 8; ++i) acc[i] = (f32x4){0.f, 0.f, 0.f, 0.f};
    float mrun[4], lrun[4];
#pragma unroll
    for (int i = 0; i < 4; ++i) { mrun[i] = -3.0e38f; lrun[i] = 0.f; }

    // prologue: stage tile 0 into cur
#pragma unroll
    for (int p = 0; p < 4; ++p) {
      gl_lds16(Kbase + kSrc[p], &Klds[cur][(p * 256 + wid * 64) * 8]);
      gl_lds16(Vbase + vSrc[p], &Vlds[cur][(p * 256 + wid * 64) * 8]);
    }
    asm volatile("s_waitcnt vmcnt(0)" ::: "memory");
    __syncthreads();

#pragma unroll 1
    for (int st = 0; st <= qt; ++st) {
      // issue next tile's staging into the other buffer (overlaps compute)
      if (st < qt) {
        const size_t ks = (size_t)(st + 1) * 64 * HD_;
        const size_t vs = (size_t)(st + 1) * 64;
#pragma unroll
        for (int p = 0; p < 4; ++p) {
          gl_lds16(Kbase + ks + kSrc[p], &Klds[cur ^ 1][(p * 256 + wid * 64) * 8]);
          gl_lds16(Vbase + vs + vSrc[p], &Vlds[cur ^ 1][(p * 256 + wid * 64) * 8]);
        }
      }

      // S = Q K^T
      f32x4 s[4];
#pragma unroll
      for (int sb = 0; sb < 4; ++sb) s[sb] = (f32x4){0.f, 0.f, 0.f, 0.f};
#pragma unroll
      for (int sb = 0; sb < 4; ++sb) {
        const int srow = sb * 16 + r;
#pragma unroll
        for (int kk = 0; kk < 4; ++kk) {
          bf16x8 kf = *(const bf16x8*)&Klds[cur][srow * 128 + (((kk * 4 + g) ^ (srow & 7)) * 8)];
          s[sb] = __builtin_amdgcn_mfma_f32_16x16x32_bf16(qf[kk], kf, s[sb], 0, 0, 0);
        }
      }

      // scale to log2 domain + causal mask on diagonal tile
      float sv[4][4];
#pragma unroll
      for (int sb = 0; sb < 4; ++sb)
#pragma unroll
        for (int rr = 0; rr < 4; ++rr) {
          float x = s[sb][rr] * SC2;
          if (st == qt) {
            int s_loc = sb * 16 + r, q_loc = wid * 16 + g * 4 + rr;
            if (s_loc > q_loc) x = -3.0e38f;
          }
          sv[sb][rr] = x;
        }

      // online softmax (rows live in 16-lane groups)
      float mnew[4], corr[4];
#pragma unroll
      for (int rr = 0; rr < 4; ++rr) {
        float mx = fmaxf(fmaxf(sv[0][rr], sv[1][rr]), fmaxf(sv[2][rr], sv[3][rr]));
#pragma unroll
        for (int d = 1; d < 16; d <<= 1) mx = fmaxf(mx, __shfl_xor(mx, d));
        mnew[rr] = fmaxf(mrun[rr], mx);
        corr[rr] = exp2_fast(mrun[rr] - mnew[rr]);
        mrun[rr] = mnew[rr];
      }
      float pv[4][4];
#pragma unroll
      for (int sb = 0; sb < 4; ++sb)
#pragma unroll
        for (int rr = 0; rr < 4; ++rr) pv[sb][rr] = exp2_fast(sv[sb][rr] - mnew[rr]);
#pragma unroll
      for (int rr = 0; rr < 4; ++rr) {
        float sum = (pv[0][rr] + pv[1][rr]) + (pv[2][rr] + pv[3][rr]);
#pragma unroll
        for (int d = 1; d < 16; d <<= 1) sum += __shfl_xor(sum, d);
        lrun[rr] = lrun[rr] * corr[rr] + sum;
      }
#pragma unroll
      for (int nb = 0; nb < 8; ++nb)
#pragma unroll
        for (int rr = 0; rr < 4; ++rr) acc[nb][rr] *= corr[rr];

      // P: C-frag -> A-frag layout via per-wave LDS round-trip
#pragma unroll
      for (int sb = 0; sb < 4; ++sb)
#pragma unroll
        for (int rr = 0; rr < 4; ++rr)
          Plds[wid][(g * 4 + rr) * 72 + sb * 16 + r] = (bf16)pv[sb][rr];
      bf16x8 pa[2];
#pragma unroll
      for (int k2 = 0; k2 < 2; ++k2)
        pa[k2] = *(const bf16x8*)&Plds[wid][r * 72 + k2 * 32 + g * 8];

      // O += P V
#pragma unroll
      for (int nb = 0; nb < 8; ++nb) {
        const int drow = nb * 16 + r;
#pragma unroll
        for (int k2 = 0; k2 < 2; ++k2) {
          bf16x8 vf = *(const bf16x8*)&Vlds[cur][drow * 64 + (((k2 * 4 + g) ^ (drow & 7)) * 8)];
          acc[nb] = __builtin_amdgcn_mfma_f32_16x16x32_bf16(pa[k2], vf, acc[nb], 0, 0, 0);
        }
      }

      asm volatile("s_waitcnt vmcnt(0)" ::: "memory");
      __syncthreads();
      cur ^= 1;
    }

    float inv[4];
#pragma unroll
    for (int rr = 0; rr < 4; ++rr) inv[rr] = 1.0f / lrun[rr];
#pragma unroll
    for (int nb = 0; nb < 8; ++nb)
#pragma unroll
      for (int rr = 0; rr < 4; ++rr) {
        size_t row = (size_t)(b * SQ_ + q0 + wid * 16 + g * 4 + rr);
        O[row * H_ + (size_t)h * HD_ + nb * 16 + r] = (bf16)(acc[nb][rr] * inv[rr]);
      }
  }
}

extern "C" void kernel_launch(void* const* d_in, const int* in_sizes, int n_in,
                              void* d_out, int out_size, void* d_ws, size_t ws_size,
                              hipStream_t stream) {
  const float* hidden = (const float*)d_in[0];
  const float* key    = (const float*)d_in[1];
  const float* value  = (const float*)d_in[2];
  // d_in[3] = attention_mask: pure causal additive mask, applied analytically
  const float* w_q    = (const float*)d_in[4];
  const float* b_q    = (const float*)d_in[5];
  const float* w_proj = (const float*)d_in[6];
  const float* b_proj = (const float*)d_in[7];
  float* out = (float*)d_out;

  const size_t N_HID = (size_t)B_ * SQ_ * H_;
  const size_t N_W   = (size_t)H_ * H_;
  const size_t N_KV  = (size_t)BH_ * SK_ * HD_;

  bf16* hid_bf  = (bf16*)d_ws;            // [B*SQ][H]
  bf16* wq_bf   = hid_bf + N_HID;         // [H][H]
  bf16* wp_bf   = wq_bf + N_W;            // [H][H]
  bf16* k_bf    = wp_bf + N_W;            // [BH][SK][HD]
  bf16* vt_bf   = k_bf + N_KV;            // [BH][HD][SK]
  bf16* q_bf    = vt_bf + N_KV;           // [B*SQ][H]
  bf16* attn_bf = hid_bf;                 // alias: hidden consumed after GEMM1

  cvt_f32_bf16<<<2048, 256, 0, stream>>>(hidden, hid_bf, (int)(N_HID / 4));
  cvt_f32_bf16<<<1024, 256, 0, stream>>>(w_q, wq_bf, (int)(N_W / 4));
  cvt_f32_bf16<<<1024, 256, 0, stream>>>(w_proj, wp_bf, (int)(N_W / 4));
  transpose_cvt<<<dim3(SK_ / 64, HD_ / 64, BH_), 256, 0, stream>>>(key, k_bf, HD_, SK_);
  transpose_cvt<<<dim3(HD_ / 64, SK_ / 64, BH_), 256, 0, stream>>>(value, vt_bf, SK_, HD_);

  gemm_bt<bf16><<<(B_ * SQ_ / 128) * (H_ / 128), 256, 0, stream>>>(
      hid_bf, wq_bf, b_q, q_bf, B_ * SQ_, H_, H_);

  flash_attn<<<512, 256, 0, stream>>>(q_bf, k_bf, vt_bf, attn_bf);

  gemm_bt<float><<<(B_ * SQ_ / 128) * (H_ / 128), 256, 0, stream>>>(
      attn_bf, wp_bf, b_proj, out, B_ * SQ_, H_, H_);
}